// Round 8
// baseline (772.188 us; speedup 1.0000x reference)
//
#include <hip/hip_runtime.h>

typedef __attribute__((ext_vector_type(8)))  short bf16x8;   // 8 bf16 = 4 VGPRs
typedef __attribute__((ext_vector_type(16))) float f32x16;   // MFMA 32x32 C/D
typedef __attribute__((ext_vector_type(4)))  float v4f;

#define TPB    256
#define NPTS   8192
#define NB     4
#define TOTPTS (NB * NPTS)        // 32768
#define XWAVE  128                // x per wave (4 B-frags)
#define XBLK   (4 * XWAVE)        // 512 x per block
#define YTILE  512                // y per block
#define NTILES (YTILE / 32)       // 16 MFMA tiles
#define GXB    (NPTS / XBLK)      // 16
#define GYB    (NPTS / YTILE)     // 16
#define NPARTIAL ((2 * TOTPTS) / 64)

// ---------------------------------------------------------------------------
// R7 lesson: MFMA math verified (absmax unchanged) but VALU busy-time 35.4us
// ~= 166 inst/wave-tile — per-tile tmin16 trees + v_accvgpr round-trips from
// the 64-VGPR default cap. Fix: (1) element-wise running mins, tree ONCE per
// wave; (2) v_min3 pairing two y-tiles per op (8 min-ops/MFMA); (3)
// __launch_bounds__(256,2) so accumulators stay in arch VGPRs (unified file);
// (4) 4 B-frags/wave halves ds_read per MFMA. Ideal pipes/SIMD: VALU 3.8us,
// LDS 2.6us, MFMA 1.7us. Encoding (verified by R7 pass):
//   A (y, M) k: [yh0,yl0,yh0, yh1,yl1,yh1, yh2,yl2,yh2, hyh,hyl, 0...]
//   B (x, N) k: [-xh0,-xh0,-xl0, -xh1,-xh1,-xl1, -xh2,-xh2,-xl2, 1,1, 0...]
//   dot = hy - (xh.yh + xh.yl + xl.yh); C/D row = (reg&3)+8(reg>>2)+4(l>>5)
// ---------------------------------------------------------------------------

__device__ __forceinline__ short bfr(float f) {       // fp32->bf16 RNE
    unsigned u = __float_as_uint(f);
    return (short)((u + 0x7FFFu + ((u >> 16) & 1u)) >> 16);
}
__device__ __forceinline__ float bf2f(short s) {
    return __uint_as_float(((unsigned)(unsigned short)s) << 16);
}

__device__ __forceinline__ float tmin16(f32x16 d) {   // tree min of 16
    float a0 = fminf(d[0], d[1]),   a1 = fminf(d[2], d[3]);
    float a2 = fminf(d[4], d[5]),   a3 = fminf(d[6], d[7]);
    float a4 = fminf(d[8], d[9]),   a5 = fminf(d[10], d[11]);
    float a6 = fminf(d[12], d[13]), a7 = fminf(d[14], d[15]);
    float b0 = fminf(a0, a1), b1 = fminf(a2, a3);
    float b2 = fminf(a4, a5), b3 = fminf(a6, a7);
    return fminf(fminf(b0, b1), fminf(b2, b3));
}

// grid = (GXB, GYB, 2*NB) = (16, 16, 8) = 2048 blocks, 4 waves each.
// Wave owns 128 x (4 B-frags); block stages YTILE=512 y as A-frags in LDS.
__global__ void __launch_bounds__(TPB, 2) nnmin_mfma(
        const float* __restrict__ T, const float* __restrict__ P,
        unsigned* __restrict__ keys)
{
    __shared__ v4f sA[NTILES * 64];   // A-fragments, 16 KB

    const int z   = blockIdx.z;
    const int dir = z >> 2;
    const int b   = z & 3;
    const float* Xb = (dir ? P : T) + (size_t)b * NPTS * 3;
    const float* Yb = (dir ? T : P) + (size_t)b * NPTS * 3;
    const int t     = threadIdx.x;
    const int l     = t & 63;          // lane
    const int w     = t >> 6;          // wave id (0..3)
    const int ybase = blockIdx.y * YTILE;
    const int xw    = blockIdx.x * XBLK + w * XWAVE;   // wave's 128 x

    // ---- stage A-fragments: 2 y-points per thread, 2 LDS entries each ----
    for (int p = t; p < YTILE; p += TPB) {
        const float* yp = Yb + (size_t)(ybase + p) * 3;
        float y0 = yp[0], y1 = yp[1], y2 = yp[2];
        short yh0 = bfr(y0); short yl0 = bfr(y0 - bf2f(yh0));
        short yh1 = bfr(y1); short yl1 = bfr(y1 - bf2f(yh1));
        short yh2 = bfr(y2); short yl2 = bfr(y2 - bf2f(yh2));
        float hy  = 0.5f * (y0 * y0 + y1 * y1 + y2 * y2);
        short hyh = bfr(hy); short hyl = bfr(hy - bf2f(hyh));
        int tile = p >> 5, m = p & 31;
        union { short s[8]; v4f v; } e0, e1;
        e0.s[0] = yh0; e0.s[1] = yl0; e0.s[2] = yh0; e0.s[3] = yh1;
        e0.s[4] = yl1; e0.s[5] = yh1; e0.s[6] = yh2; e0.s[7] = yl2;
        e1.s[0] = yh2; e1.s[1] = hyh; e1.s[2] = hyl; e1.s[3] = 0;
        e1.s[4] = 0;   e1.s[5] = 0;   e1.s[6] = 0;   e1.s[7] = 0;
        sA[tile * 64 + m]      = e0.v;   // lanes <32 read k=0..7
        sA[tile * 64 + 32 + m] = e1.v;   // lanes >=32 read k=8..15
    }

    // ---- build the wave's 4 B-fragments (x side), register-resident ----
    const int   kh  = l >> 5;          // which K-half this lane supplies
    const short ONE = 0x3F80;          // bf16(1.0)
    bf16x8 B[4];
#pragma unroll
    for (int f = 0; f < 4; ++f) {
        const float* xp = Xb + (size_t)(xw + f * 32 + (l & 31)) * 3;
        float nx = -xp[0], ny = -xp[1], nz = -xp[2];
        short h0 = bfr(nx); short lo0 = bfr(nx - bf2f(h0));
        short h1 = bfr(ny); short lo1 = bfr(ny - bf2f(h1));
        short h2 = bfr(nz); short lo2 = bfr(nz - bf2f(h2));
        union { short s[8]; bf16x8 v; } e;
        if (kh == 0) {
            e.s[0] = h0; e.s[1] = h0; e.s[2] = lo0; e.s[3] = h1;
            e.s[4] = h1; e.s[5] = lo1; e.s[6] = h2; e.s[7] = h2;
        } else {
            e.s[0] = lo2; e.s[1] = ONE; e.s[2] = ONE; e.s[3] = 0;
            e.s[4] = 0;   e.s[5] = 0;   e.s[6] = 0;   e.s[7] = 0;
        }
        B[f] = e.v;
    }
    __syncthreads();

    // ---- main loop: per 2-tile iter: 2 ds_read_b128 + 8 MFMA + 64 min3 ----
    f32x16 zero = {0.f};               // loop-invariant C input (VGPRs)
    f32x16 rm[4];
#pragma unroll
    for (int f = 0; f < 4; ++f)
#pragma unroll
        for (int i = 0; i < 16; ++i) rm[f][i] = 3.0e38f;

#pragma unroll
    for (int tl = 0; tl < NTILES; tl += 2) {
        v4f a4a = sA[(tl + 0) * 64 + l];
        v4f a4b = sA[(tl + 1) * 64 + l];
        bf16x8 Aa = *(bf16x8*)&a4a;
        bf16x8 Ab = *(bf16x8*)&a4b;
#pragma unroll
        for (int f = 0; f < 4; ++f) {
            f32x16 da = __builtin_amdgcn_mfma_f32_32x32x16_bf16(Aa, B[f], zero, 0, 0, 0);
            f32x16 db = __builtin_amdgcn_mfma_f32_32x32x16_bf16(Ab, B[f], zero, 0, 0, 0);
#pragma unroll
            for (int i = 0; i < 16; ++i)                 // v_min3_f32 pattern
                rm[f][i] = fminf(rm[f][i], fminf(da[i], db[i]));
        }
    }

    // ---- epilogue (once per wave): tree-min + cross-half + atomic ----
    unsigned* o = keys + (size_t)dir * TOTPTS + (size_t)b * NPTS;
#pragma unroll
    for (int f = 0; f < 4; ++f) {
        float v = tmin16(rm[f]);
        v = fminf(v, __shfl_xor(v, 32, 64));   // rows split across lane halves
        if (l < 32) {
            unsigned bb = __float_as_uint(v);
            atomicMin(&o[xw + f * 32 + l],
                      bb ^ ((bb & 0x80000000u) ? 0xFFFFFFFFu : 0x80000000u));
        }
    }
}

// Decode key, add hx, sqrt; write mins_seeds; per-wave partial sums.
__global__ void __launch_bounds__(TPB) finalize_kernel(
        const unsigned* __restrict__ keys,
        const float* __restrict__ T, const float* __restrict__ P,
        float* __restrict__ out, float* __restrict__ partials)
{
    int i   = blockIdx.x * TPB + threadIdx.x;   // 0 .. 2*TOTPTS-1
    int dir = (i >= TOTPTS) ? 1 : 0;            // uniform per block
    int idx = i - dir * TOTPTS;
    int b   = idx >> 13;
    int x   = idx & (NPTS - 1);

    unsigned k  = keys[i];
    unsigned bb = (k & 0x80000000u) ? (k ^ 0x80000000u) : ~k;
    float m = __uint_as_float(bb);

    const float* xp = (dir ? P : T) + ((size_t)b * NPTS + x) * 3;
    float a0 = xp[0], a1 = xp[1], a2 = xp[2];
    float hx = 0.5f * (a0 * a0 + a1 * a1 + a2 * a2);
    float d  = sqrtf(fmaxf(2.0f * (hx + m), 0.0f));
    if (dir) out[1 + idx] = d;                  // mins_seeds

#pragma unroll
    for (int off = 32; off > 0; off >>= 1)
        d += __shfl_down(d, off, 64);
    if ((threadIdx.x & 63) == 0) partials[i >> 6] = d;
}

__global__ void scalar_kernel(const float* __restrict__ partials,
                              float* __restrict__ out) {
    int t = threadIdx.x;                        // 64 threads
    float s = 0.0f;
#pragma unroll
    for (int k = 0; k < NPARTIAL / 64; ++k)
        s += partials[t * (NPARTIAL / 64) + k];
#pragma unroll
    for (int off = 32; off > 0; off >>= 1)
        s += __shfl_down(s, off, 64);
    if (t == 0) out[0] = s * (1.0f / (float)TOTPTS);
}

extern "C" void kernel_launch(void* const* d_in, const int* in_sizes, int n_in,
                              void* d_out, int out_size, void* d_ws, size_t ws_size,
                              hipStream_t stream) {
    const float* truep = (const float*)d_in[0];   // [4, 8192, 3] fp32
    const float* predp = (const float*)d_in[1];   // [4, 8192, 3] fp32
    float* out = (float*)d_out;                   // [1 + 32768] fp32

    unsigned* keys     = (unsigned*)d_ws;                 // 2*TOTPTS u32
    float*    partials = (float*)(keys + 2 * TOTPTS);     // 1024 floats

    // 0xFFFFFFFF = max flip-key: valid floor for atomicMin. 256 KB.
    hipMemsetAsync(keys, 0xFF, (size_t)2 * TOTPTS * 4, stream);

    dim3 grid(GXB, GYB, 2 * NB);                  // (16, 16, 8) = 2048 blocks
    nnmin_mfma<<<grid, TPB, 0, stream>>>(truep, predp, keys);

    finalize_kernel<<<(2 * TOTPTS) / TPB, TPB, 0, stream>>>(
        keys, truep, predp, out, partials);
    scalar_kernel<<<1, 64, 0, stream>>>(partials, out);
}

// Round 9
// 147.774 us; speedup vs baseline: 5.2255x; 5.2255x over previous
//
#include <hip/hip_runtime.h>

typedef __attribute__((ext_vector_type(8)))  short bf16x8;   // 8 bf16 = 4 VGPRs
typedef __attribute__((ext_vector_type(16))) float f32x16;   // MFMA 32x32 C/D
typedef __attribute__((ext_vector_type(4)))  float v4f;

#define TPB    256
#define NPTS   8192
#define NB     4
#define TOTPTS (NB * NPTS)        // 32768
#define XWAVE  64                 // x per wave (2 B-frags)  [R8: 128 spilled]
#define XBLK   (4 * XWAVE)        // 256 x per block
#define YTILE  512                // y per block
#define NTILES (YTILE / 32)       // 16 MFMA tiles
#define GXB    (NPTS / XBLK)      // 32
#define GYB    (NPTS / YTILE)     // 16
#define NPARTIAL ((2 * TOTPTS) / 64)

// ---------------------------------------------------------------------------
// R8 lesson: rm[4]+da/db+zero+B[4] = ~136 live VGPRs > 128 cap -> scratch
// spill (FETCH 750MB, 744us). Budget this time: rm[2](32) + da/db(32) +
// zero(16) + B[2](8) + A-pair(8) + addr ~ 110 < 128. Keep R8's good ideas:
// element-wise running min (tree ONCE per wave), v_min3 tile-pairing
// (8 min-ops/MFMA), launch_bounds(256,2) so accumulators stay in arch VGPRs.
// Pipes ideal: LDS 5.1us (binding), min3 3.4us, MFMA 1.7us.
// Encoding (HW-verified by R7 pass):
//   A (y, M) k: [yh0,yl0,yh0, yh1,yl1,yh1, yh2,yl2,yh2, hyh,hyl, 0...]
//   B (x, N) k: [-xh0,-xh0,-xl0, -xh1,-xh1,-xl1, -xh2,-xh2,-xl2, 1,1, 0...]
//   dot = hy - (xh.yh + xh.yl + xl.yh); C/D row = (reg&3)+8(reg>>2)+4(l>>5)
// ---------------------------------------------------------------------------

__device__ __forceinline__ short bfr(float f) {       // fp32->bf16 RNE
    unsigned u = __float_as_uint(f);
    return (short)((u + 0x7FFFu + ((u >> 16) & 1u)) >> 16);
}
__device__ __forceinline__ float bf2f(short s) {
    return __uint_as_float(((unsigned)(unsigned short)s) << 16);
}

__device__ __forceinline__ float tmin16(f32x16 d) {   // tree min of 16
    float a0 = fminf(d[0], d[1]),   a1 = fminf(d[2], d[3]);
    float a2 = fminf(d[4], d[5]),   a3 = fminf(d[6], d[7]);
    float a4 = fminf(d[8], d[9]),   a5 = fminf(d[10], d[11]);
    float a6 = fminf(d[12], d[13]), a7 = fminf(d[14], d[15]);
    float b0 = fminf(a0, a1), b1 = fminf(a2, a3);
    float b2 = fminf(a4, a5), b3 = fminf(a6, a7);
    return fminf(fminf(b0, b1), fminf(b2, b3));
}

// grid = (GXB, GYB, 2*NB) = (32, 16, 8) = 4096 blocks, 4 waves each.
// Wave owns 64 x (2 B-frags); block stages YTILE=512 y as A-frags in LDS.
__global__ void __launch_bounds__(TPB, 2) nnmin_mfma(
        const float* __restrict__ T, const float* __restrict__ P,
        unsigned* __restrict__ keys)
{
    __shared__ v4f sA[NTILES * 64];   // A-fragments, 16 KB

    const int z   = blockIdx.z;
    const int dir = z >> 2;
    const int b   = z & 3;
    const float* Xb = (dir ? P : T) + (size_t)b * NPTS * 3;
    const float* Yb = (dir ? T : P) + (size_t)b * NPTS * 3;
    const int t     = threadIdx.x;
    const int l     = t & 63;          // lane
    const int w     = t >> 6;          // wave id (0..3)
    const int ybase = blockIdx.y * YTILE;
    const int xw    = blockIdx.x * XBLK + w * XWAVE;   // wave's 64 x

    // ---- stage A-fragments: 2 y-points per thread, 2 LDS entries each ----
    for (int p = t; p < YTILE; p += TPB) {
        const float* yp = Yb + (size_t)(ybase + p) * 3;
        float y0 = yp[0], y1 = yp[1], y2 = yp[2];
        short yh0 = bfr(y0); short yl0 = bfr(y0 - bf2f(yh0));
        short yh1 = bfr(y1); short yl1 = bfr(y1 - bf2f(yh1));
        short yh2 = bfr(y2); short yl2 = bfr(y2 - bf2f(yh2));
        float hy  = 0.5f * (y0 * y0 + y1 * y1 + y2 * y2);
        short hyh = bfr(hy); short hyl = bfr(hy - bf2f(hyh));
        int tile = p >> 5, m = p & 31;
        union { short s[8]; v4f v; } e0, e1;
        e0.s[0] = yh0; e0.s[1] = yl0; e0.s[2] = yh0; e0.s[3] = yh1;
        e0.s[4] = yl1; e0.s[5] = yh1; e0.s[6] = yh2; e0.s[7] = yl2;
        e1.s[0] = yh2; e1.s[1] = hyh; e1.s[2] = hyl; e1.s[3] = 0;
        e1.s[4] = 0;   e1.s[5] = 0;   e1.s[6] = 0;   e1.s[7] = 0;
        sA[tile * 64 + m]      = e0.v;   // lanes <32 read k=0..7
        sA[tile * 64 + 32 + m] = e1.v;   // lanes >=32 read k=8..15
    }

    // ---- build the wave's 2 B-fragments (x side), register-resident ----
    const int   kh  = l >> 5;          // which K-half this lane supplies
    const short ONE = 0x3F80;          // bf16(1.0)
    bf16x8 B[2];
#pragma unroll
    for (int f = 0; f < 2; ++f) {
        const float* xp = Xb + (size_t)(xw + f * 32 + (l & 31)) * 3;
        float nx = -xp[0], ny = -xp[1], nz = -xp[2];
        short h0 = bfr(nx); short lo0 = bfr(nx - bf2f(h0));
        short h1 = bfr(ny); short lo1 = bfr(ny - bf2f(h1));
        short h2 = bfr(nz); short lo2 = bfr(nz - bf2f(h2));
        union { short s[8]; bf16x8 v; } e;
        if (kh == 0) {
            e.s[0] = h0; e.s[1] = h0; e.s[2] = lo0; e.s[3] = h1;
            e.s[4] = h1; e.s[5] = lo1; e.s[6] = h2; e.s[7] = h2;
        } else {
            e.s[0] = lo2; e.s[1] = ONE; e.s[2] = ONE; e.s[3] = 0;
            e.s[4] = 0;   e.s[5] = 0;   e.s[6] = 0;   e.s[7] = 0;
        }
        B[f] = e.v;
    }
    __syncthreads();

    // ---- main loop: per 2-tile iter: 2 ds_read_b128 + 4 MFMA + 32 min3 ----
    f32x16 zero = {0.f};               // loop-invariant C input (VGPRs)
    f32x16 rm[2];
#pragma unroll
    for (int f = 0; f < 2; ++f)
#pragma unroll
        for (int i = 0; i < 16; ++i) rm[f][i] = 3.0e38f;

#pragma unroll
    for (int tl = 0; tl < NTILES; tl += 2) {
        v4f a4a = sA[(tl + 0) * 64 + l];
        v4f a4b = sA[(tl + 1) * 64 + l];
        bf16x8 Aa = *(bf16x8*)&a4a;
        bf16x8 Ab = *(bf16x8*)&a4b;
#pragma unroll
        for (int f = 0; f < 2; ++f) {
            f32x16 da = __builtin_amdgcn_mfma_f32_32x32x16_bf16(Aa, B[f], zero, 0, 0, 0);
            f32x16 db = __builtin_amdgcn_mfma_f32_32x32x16_bf16(Ab, B[f], zero, 0, 0, 0);
#pragma unroll
            for (int i = 0; i < 16; ++i)                 // v_min3_f32 pattern
                rm[f][i] = fminf(rm[f][i], fminf(da[i], db[i]));
        }
    }

    // ---- epilogue (once per wave): tree-min + cross-half + atomic ----
    unsigned* o = keys + (size_t)dir * TOTPTS + (size_t)b * NPTS;
#pragma unroll
    for (int f = 0; f < 2; ++f) {
        float v = tmin16(rm[f]);
        v = fminf(v, __shfl_xor(v, 32, 64));   // rows split across lane halves
        if (l < 32) {
            unsigned bb = __float_as_uint(v);
            atomicMin(&o[xw + f * 32 + l],
                      bb ^ ((bb & 0x80000000u) ? 0xFFFFFFFFu : 0x80000000u));
        }
    }
}

// Decode key, add hx, sqrt; write mins_seeds; per-wave partial sums.
__global__ void __launch_bounds__(TPB) finalize_kernel(
        const unsigned* __restrict__ keys,
        const float* __restrict__ T, const float* __restrict__ P,
        float* __restrict__ out, float* __restrict__ partials)
{
    int i   = blockIdx.x * TPB + threadIdx.x;   // 0 .. 2*TOTPTS-1
    int dir = (i >= TOTPTS) ? 1 : 0;            // uniform per block
    int idx = i - dir * TOTPTS;
    int b   = idx >> 13;
    int x   = idx & (NPTS - 1);

    unsigned k  = keys[i];
    unsigned bb = (k & 0x80000000u) ? (k ^ 0x80000000u) : ~k;
    float m = __uint_as_float(bb);

    const float* xp = (dir ? P : T) + ((size_t)b * NPTS + x) * 3;
    float a0 = xp[0], a1 = xp[1], a2 = xp[2];
    float hx = 0.5f * (a0 * a0 + a1 * a1 + a2 * a2);
    float d  = sqrtf(fmaxf(2.0f * (hx + m), 0.0f));
    if (dir) out[1 + idx] = d;                  // mins_seeds

#pragma unroll
    for (int off = 32; off > 0; off >>= 1)
        d += __shfl_down(d, off, 64);
    if ((threadIdx.x & 63) == 0) partials[i >> 6] = d;
}

__global__ void scalar_kernel(const float* __restrict__ partials,
                              float* __restrict__ out) {
    int t = threadIdx.x;                        // 64 threads
    float s = 0.0f;
#pragma unroll
    for (int k = 0; k < NPARTIAL / 64; ++k)
        s += partials[t * (NPARTIAL / 64) + k];
#pragma unroll
    for (int off = 32; off > 0; off >>= 1)
        s += __shfl_down(s, off, 64);
    if (t == 0) out[0] = s * (1.0f / (float)TOTPTS);
}

extern "C" void kernel_launch(void* const* d_in, const int* in_sizes, int n_in,
                              void* d_out, int out_size, void* d_ws, size_t ws_size,
                              hipStream_t stream) {
    const float* truep = (const float*)d_in[0];   // [4, 8192, 3] fp32
    const float* predp = (const float*)d_in[1];   // [4, 8192, 3] fp32
    float* out = (float*)d_out;                   // [1 + 32768] fp32

    unsigned* keys     = (unsigned*)d_ws;                 // 2*TOTPTS u32
    float*    partials = (float*)(keys + 2 * TOTPTS);     // 1024 floats

    // 0xFFFFFFFF = max flip-key: valid floor for atomicMin. 256 KB.
    hipMemsetAsync(keys, 0xFF, (size_t)2 * TOTPTS * 4, stream);

    dim3 grid(GXB, GYB, 2 * NB);                  // (32, 16, 8) = 4096 blocks
    nnmin_mfma<<<grid, TPB, 0, stream>>>(truep, predp, keys);

    finalize_kernel<<<(2 * TOTPTS) / TPB, TPB, 0, stream>>>(
        keys, truep, predp, out, partials);
    scalar_kernel<<<1, 64, 0, stream>>>(partials, out);
}

// Round 10
// 101.843 us; speedup vs baseline: 7.5822x; 1.4510x over previous
//
#include <hip/hip_runtime.h>

typedef __attribute__((ext_vector_type(8)))  short bf16x8;   // 8 bf16 = 4 VGPRs
typedef __attribute__((ext_vector_type(16))) float f32x16;   // MFMA 32x32 C/D
typedef __attribute__((ext_vector_type(4)))  float v4f;

#define TPB    256
#define NPTS   8192
#define NB     4
#define TOTPTS (NB * NPTS)        // 32768
#define XWAVE  64                 // x per wave (2 B-frags)
#define XBLK   (4 * XWAVE)        // 256 x per block
#define YTILE  512                // y per block
#define NTILES (YTILE / 32)       // 16 MFMA tiles
#define GXB    (NPTS / XBLK)      // 32
#define GYB    (NPTS / YTILE)     // 16
#define NPARTIAL ((2 * TOTPTS) / 64)

// ---------------------------------------------------------------------------
// R9 lesson: spill persisted (WRITE 194MB) because (a) launch_bounds(256,2)
// let the allocator settle at 128 regs, split arch/acc for MFMA -> ~64 arch
// VGPRs for the min-stream; (b) full unroll hoisted ALL 16 ds_read A-frags
// (64 live regs) to the loop head. Fix: launch_bounds(256,1) -> 512-reg cap
// (runtime occupancy still ~3 waves/SIMD at ~160 used; spill costs more than
// the occupancy step), and #pragma unroll 2 to bound A-frag hoisting.
// Keep: element-wise running min (tree once/wave), v_min3 tile-pairing,
// flip-key atomicMin combine. Pipes ideal: LDS 5.1us, min3 3.4us, MFMA 1.7us.
// Encoding (HW-verified by R7 pass):
//   A (y, M) k: [yh0,yl0,yh0, yh1,yl1,yh1, yh2,yl2,yh2, hyh,hyl, 0...]
//   B (x, N) k: [-xh0,-xh0,-xl0, -xh1,-xh1,-xl1, -xh2,-xh2,-xl2, 1,1, 0...]
//   dot = hy - (xh.yh + xh.yl + xl.yh); C/D row = (reg&3)+8(reg>>2)+4(l>>5)
// ---------------------------------------------------------------------------

__device__ __forceinline__ short bfr(float f) {       // fp32->bf16 RNE
    unsigned u = __float_as_uint(f);
    return (short)((u + 0x7FFFu + ((u >> 16) & 1u)) >> 16);
}
__device__ __forceinline__ float bf2f(short s) {
    return __uint_as_float(((unsigned)(unsigned short)s) << 16);
}

__device__ __forceinline__ float tmin16(f32x16 d) {   // tree min of 16
    float a0 = fminf(d[0], d[1]),   a1 = fminf(d[2], d[3]);
    float a2 = fminf(d[4], d[5]),   a3 = fminf(d[6], d[7]);
    float a4 = fminf(d[8], d[9]),   a5 = fminf(d[10], d[11]);
    float a6 = fminf(d[12], d[13]), a7 = fminf(d[14], d[15]);
    float b0 = fminf(a0, a1), b1 = fminf(a2, a3);
    float b2 = fminf(a4, a5), b3 = fminf(a6, a7);
    return fminf(fminf(b0, b1), fminf(b2, b3));
}

// grid = (GXB, GYB, 2*NB) = (32, 16, 8) = 4096 blocks, 4 waves each.
// Wave owns 64 x (2 B-frags); block stages YTILE=512 y as A-frags in LDS.
__global__ void __launch_bounds__(TPB, 1) nnmin_mfma(
        const float* __restrict__ T, const float* __restrict__ P,
        unsigned* __restrict__ keys)
{
    __shared__ v4f sA[NTILES * 64];   // A-fragments, 16 KB

    const int z   = blockIdx.z;
    const int dir = z >> 2;
    const int b   = z & 3;
    const float* Xb = (dir ? P : T) + (size_t)b * NPTS * 3;
    const float* Yb = (dir ? T : P) + (size_t)b * NPTS * 3;
    const int t     = threadIdx.x;
    const int l     = t & 63;          // lane
    const int w     = t >> 6;          // wave id (0..3)
    const int ybase = blockIdx.y * YTILE;
    const int xw    = blockIdx.x * XBLK + w * XWAVE;   // wave's 64 x

    // ---- stage A-fragments: 2 y-points per thread, 2 LDS entries each ----
    for (int p = t; p < YTILE; p += TPB) {
        const float* yp = Yb + (size_t)(ybase + p) * 3;
        float y0 = yp[0], y1 = yp[1], y2 = yp[2];
        short yh0 = bfr(y0); short yl0 = bfr(y0 - bf2f(yh0));
        short yh1 = bfr(y1); short yl1 = bfr(y1 - bf2f(yh1));
        short yh2 = bfr(y2); short yl2 = bfr(y2 - bf2f(yh2));
        float hy  = 0.5f * (y0 * y0 + y1 * y1 + y2 * y2);
        short hyh = bfr(hy); short hyl = bfr(hy - bf2f(hyh));
        int tile = p >> 5, m = p & 31;
        union { short s[8]; v4f v; } e0, e1;
        e0.s[0] = yh0; e0.s[1] = yl0; e0.s[2] = yh0; e0.s[3] = yh1;
        e0.s[4] = yl1; e0.s[5] = yh1; e0.s[6] = yh2; e0.s[7] = yl2;
        e1.s[0] = yh2; e1.s[1] = hyh; e1.s[2] = hyl; e1.s[3] = 0;
        e1.s[4] = 0;   e1.s[5] = 0;   e1.s[6] = 0;   e1.s[7] = 0;
        sA[tile * 64 + m]      = e0.v;   // lanes <32 read k=0..7
        sA[tile * 64 + 32 + m] = e1.v;   // lanes >=32 read k=8..15
    }

    // ---- build the wave's 2 B-fragments (x side), register-resident ----
    const int   kh  = l >> 5;          // which K-half this lane supplies
    const short ONE = 0x3F80;          // bf16(1.0)
    bf16x8 B[2];
#pragma unroll
    for (int f = 0; f < 2; ++f) {
        const float* xp = Xb + (size_t)(xw + f * 32 + (l & 31)) * 3;
        float nx = -xp[0], ny = -xp[1], nz = -xp[2];
        short h0 = bfr(nx); short lo0 = bfr(nx - bf2f(h0));
        short h1 = bfr(ny); short lo1 = bfr(ny - bf2f(h1));
        short h2 = bfr(nz); short lo2 = bfr(nz - bf2f(h2));
        union { short s[8]; bf16x8 v; } e;
        if (kh == 0) {
            e.s[0] = h0; e.s[1] = h0; e.s[2] = lo0; e.s[3] = h1;
            e.s[4] = h1; e.s[5] = lo1; e.s[6] = h2; e.s[7] = h2;
        } else {
            e.s[0] = lo2; e.s[1] = ONE; e.s[2] = ONE; e.s[3] = 0;
            e.s[4] = 0;   e.s[5] = 0;   e.s[6] = 0;   e.s[7] = 0;
        }
        B[f] = e.v;
    }
    __syncthreads();

    // ---- main loop: per 2-tile iter: 2 ds_read_b128 + 4 MFMA + 32 min3 ----
    f32x16 zero = {0.f};               // loop-invariant C input
    f32x16 rm[2];
#pragma unroll
    for (int f = 0; f < 2; ++f)
#pragma unroll
        for (int i = 0; i < 16; ++i) rm[f][i] = 3.0e38f;

#pragma unroll 2                       // bound A-frag hoisting (R9 spilled)
    for (int tl = 0; tl < NTILES; tl += 2) {
        v4f a4a = sA[(tl + 0) * 64 + l];
        v4f a4b = sA[(tl + 1) * 64 + l];
        bf16x8 Aa = *(bf16x8*)&a4a;
        bf16x8 Ab = *(bf16x8*)&a4b;
#pragma unroll
        for (int f = 0; f < 2; ++f) {
            f32x16 da = __builtin_amdgcn_mfma_f32_32x32x16_bf16(Aa, B[f], zero, 0, 0, 0);
            f32x16 db = __builtin_amdgcn_mfma_f32_32x32x16_bf16(Ab, B[f], zero, 0, 0, 0);
#pragma unroll
            for (int i = 0; i < 16; ++i)                 // v_min3_f32 pattern
                rm[f][i] = fminf(rm[f][i], fminf(da[i], db[i]));
        }
    }

    // ---- epilogue (once per wave): tree-min + cross-half + atomic ----
    unsigned* o = keys + (size_t)dir * TOTPTS + (size_t)b * NPTS;
#pragma unroll
    for (int f = 0; f < 2; ++f) {
        float v = tmin16(rm[f]);
        v = fminf(v, __shfl_xor(v, 32, 64));   // rows split across lane halves
        if (l < 32) {
            unsigned bb = __float_as_uint(v);
            atomicMin(&o[xw + f * 32 + l],
                      bb ^ ((bb & 0x80000000u) ? 0xFFFFFFFFu : 0x80000000u));
        }
    }
}

// Decode key, add hx, sqrt; write mins_seeds; per-wave partial sums.
__global__ void __launch_bounds__(TPB) finalize_kernel(
        const unsigned* __restrict__ keys,
        const float* __restrict__ T, const float* __restrict__ P,
        float* __restrict__ out, float* __restrict__ partials)
{
    int i   = blockIdx.x * TPB + threadIdx.x;   // 0 .. 2*TOTPTS-1
    int dir = (i >= TOTPTS) ? 1 : 0;            // uniform per block
    int idx = i - dir * TOTPTS;
    int b   = idx >> 13;
    int x   = idx & (NPTS - 1);

    unsigned k  = keys[i];
    unsigned bb = (k & 0x80000000u) ? (k ^ 0x80000000u) : ~k;
    float m = __uint_as_float(bb);

    const float* xp = (dir ? P : T) + ((size_t)b * NPTS + x) * 3;
    float a0 = xp[0], a1 = xp[1], a2 = xp[2];
    float hx = 0.5f * (a0 * a0 + a1 * a1 + a2 * a2);
    float d  = sqrtf(fmaxf(2.0f * (hx + m), 0.0f));
    if (dir) out[1 + idx] = d;                  // mins_seeds

#pragma unroll
    for (int off = 32; off > 0; off >>= 1)
        d += __shfl_down(d, off, 64);
    if ((threadIdx.x & 63) == 0) partials[i >> 6] = d;
}

__global__ void scalar_kernel(const float* __restrict__ partials,
                              float* __restrict__ out) {
    int t = threadIdx.x;                        // 64 threads
    float s = 0.0f;
#pragma unroll
    for (int k = 0; k < NPARTIAL / 64; ++k)
        s += partials[t * (NPARTIAL / 64) + k];
#pragma unroll
    for (int off = 32; off > 0; off >>= 1)
        s += __shfl_down(s, off, 64);
    if (t == 0) out[0] = s * (1.0f / (float)TOTPTS);
}

extern "C" void kernel_launch(void* const* d_in, const int* in_sizes, int n_in,
                              void* d_out, int out_size, void* d_ws, size_t ws_size,
                              hipStream_t stream) {
    const float* truep = (const float*)d_in[0];   // [4, 8192, 3] fp32
    const float* predp = (const float*)d_in[1];   // [4, 8192, 3] fp32
    float* out = (float*)d_out;                   // [1 + 32768] fp32

    unsigned* keys     = (unsigned*)d_ws;                 // 2*TOTPTS u32
    float*    partials = (float*)(keys + 2 * TOTPTS);     // 1024 floats

    // 0xFFFFFFFF = max flip-key: valid floor for atomicMin. 256 KB.
    hipMemsetAsync(keys, 0xFF, (size_t)2 * TOTPTS * 4, stream);

    dim3 grid(GXB, GYB, 2 * NB);                  // (32, 16, 8) = 4096 blocks
    nnmin_mfma<<<grid, TPB, 0, stream>>>(truep, predp, keys);

    finalize_kernel<<<(2 * TOTPTS) / TPB, TPB, 0, stream>>>(
        keys, truep, predp, out, partials);
    scalar_kernel<<<1, 64, 0, stream>>>(partials, out);
}

// Round 11
// 86.804 us; speedup vs baseline: 8.8958x; 1.1733x over previous
//
#include <hip/hip_runtime.h>

typedef __attribute__((ext_vector_type(8)))  short bf16x8;   // 8 bf16 = 4 VGPRs
typedef __attribute__((ext_vector_type(16))) float f32x16;   // MFMA 32x32 C/D
typedef __attribute__((ext_vector_type(4)))  float v4f;

#define TPB    256
#define NPTS   8192
#define NB     4
#define TOTPTS (NB * NPTS)        // 32768
#define XWAVE  64                 // x per wave (2 B-frags)
#define XBLK   (4 * XWAVE)        // 256 x per block
#define YTILE  512                // y per block
#define NTILES (YTILE / 32)       // 16 MFMA tiles
#define GXB    (NPTS / XBLK)      // 32
#define GYB    (NPTS / YTILE)     // 16
#define NPARTIAL ((2 * TOTPTS) / 64)

// ---------------------------------------------------------------------------
// R10 lesson: no spill, but VALU busy 43.5us (~3260 inst/wave) — allocator
// chose AGPR-form MFMA (VGPR_Count=60) and kept rm in AGPRs: ~5 inst per 2
// outputs (reads + rm RMW), no min3 fusion. Invariant: acc-form VALU floor =
// 1.5 inst/output (2 accvgpr_read + 0.5 v_min3) = 10.2us busy. Fix: pin the
// combine with per-element inline asm v_min3_f32 on "v" constraints — forces
// da/db into arch VGPRs via exactly one compiler-emitted accvgpr_read each
// (hazard-safe: MFMA consumer is compiler code), forces rm to arch VGPRs,
// guarantees min3. MFMA stays a builtin (hazards handled). unroll 2 bounds
// ds_read hoisting (R9 spill); launch_bounds(256,1) uncaps arch regs.
// Encoding (HW-verified by R7 pass):
//   A (y, M) k: [yh0,yl0,yh0, yh1,yl1,yh1, yh2,yl2,yh2, hyh,hyl, 0...]
//   B (x, N) k: [-xh0,-xh0,-xl0, -xh1,-xh1,-xl1, -xh2,-xh2,-xl2, 1,1, 0...]
//   dot = hy - (xh.yh + xh.yl + xl.yh); C/D row = (reg&3)+8(reg>>2)+4(l>>5)
// ---------------------------------------------------------------------------

__device__ __forceinline__ short bfr(float f) {       // fp32->bf16 RNE
    unsigned u = __float_as_uint(f);
    return (short)((u + 0x7FFFu + ((u >> 16) & 1u)) >> 16);
}
__device__ __forceinline__ float bf2f(short s) {
    return __uint_as_float(((unsigned)(unsigned short)s) << 16);
}

// grid = (GXB, GYB, 2*NB) = (32, 16, 8) = 4096 blocks, 4 waves each.
// Wave owns 64 x (2 B-frags); block stages YTILE=512 y as A-frags in LDS.
__global__ void __launch_bounds__(TPB, 1) nnmin_mfma(
        const float* __restrict__ T, const float* __restrict__ P,
        unsigned* __restrict__ keys)
{
    __shared__ v4f sA[NTILES * 64];   // A-fragments, 16 KB

    const int z   = blockIdx.z;
    const int dir = z >> 2;
    const int b   = z & 3;
    const float* Xb = (dir ? P : T) + (size_t)b * NPTS * 3;
    const float* Yb = (dir ? T : P) + (size_t)b * NPTS * 3;
    const int t     = threadIdx.x;
    const int l     = t & 63;          // lane
    const int w     = t >> 6;          // wave id (0..3)
    const int ybase = blockIdx.y * YTILE;
    const int xw    = blockIdx.x * XBLK + w * XWAVE;   // wave's 64 x

    // ---- stage A-fragments: 2 y-points per thread, 2 LDS entries each ----
    for (int p = t; p < YTILE; p += TPB) {
        const float* yp = Yb + (size_t)(ybase + p) * 3;
        float y0 = yp[0], y1 = yp[1], y2 = yp[2];
        short yh0 = bfr(y0); short yl0 = bfr(y0 - bf2f(yh0));
        short yh1 = bfr(y1); short yl1 = bfr(y1 - bf2f(yh1));
        short yh2 = bfr(y2); short yl2 = bfr(y2 - bf2f(yh2));
        float hy  = 0.5f * (y0 * y0 + y1 * y1 + y2 * y2);
        short hyh = bfr(hy); short hyl = bfr(hy - bf2f(hyh));
        int tile = p >> 5, m = p & 31;
        union { short s[8]; v4f v; } e0, e1;
        e0.s[0] = yh0; e0.s[1] = yl0; e0.s[2] = yh0; e0.s[3] = yh1;
        e0.s[4] = yl1; e0.s[5] = yh1; e0.s[6] = yh2; e0.s[7] = yl2;
        e1.s[0] = yh2; e1.s[1] = hyh; e1.s[2] = hyl; e1.s[3] = 0;
        e1.s[4] = 0;   e1.s[5] = 0;   e1.s[6] = 0;   e1.s[7] = 0;
        sA[tile * 64 + m]      = e0.v;   // lanes <32 read k=0..7
        sA[tile * 64 + 32 + m] = e1.v;   // lanes >=32 read k=8..15
    }

    // ---- build the wave's 2 B-fragments (x side), register-resident ----
    const int   kh  = l >> 5;          // which K-half this lane supplies
    const short ONE = 0x3F80;          // bf16(1.0)
    bf16x8 B[2];
#pragma unroll
    for (int f = 0; f < 2; ++f) {
        const float* xp = Xb + (size_t)(xw + f * 32 + (l & 31)) * 3;
        float nx = -xp[0], ny = -xp[1], nz = -xp[2];
        short h0 = bfr(nx); short lo0 = bfr(nx - bf2f(h0));
        short h1 = bfr(ny); short lo1 = bfr(ny - bf2f(h1));
        short h2 = bfr(nz); short lo2 = bfr(nz - bf2f(h2));
        union { short s[8]; bf16x8 v; } e;
        if (kh == 0) {
            e.s[0] = h0; e.s[1] = h0; e.s[2] = lo0; e.s[3] = h1;
            e.s[4] = h1; e.s[5] = lo1; e.s[6] = h2; e.s[7] = h2;
        } else {
            e.s[0] = lo2; e.s[1] = ONE; e.s[2] = ONE; e.s[3] = 0;
            e.s[4] = 0;   e.s[5] = 0;   e.s[6] = 0;   e.s[7] = 0;
        }
        B[f] = e.v;
    }
    __syncthreads();

    // ---- main loop: 2 ds_read_b128 + 4 MFMA + 64 accvgpr_read + 32 min3 ----
    f32x16 zero = {0.f};               // loop-invariant C input
    float rm[2][16];                   // running mins — pinned to arch VGPRs
#pragma unroll
    for (int f = 0; f < 2; ++f)
#pragma unroll
        for (int i = 0; i < 16; ++i) rm[f][i] = 3.0e38f;

#pragma unroll 2                       // bound A-frag hoisting (R9 spilled)
    for (int tl = 0; tl < NTILES; tl += 2) {
        v4f a4a = sA[(tl + 0) * 64 + l];
        v4f a4b = sA[(tl + 1) * 64 + l];
        bf16x8 Aa = *(bf16x8*)&a4a;
        bf16x8 Ab = *(bf16x8*)&a4b;
#pragma unroll
        for (int f = 0; f < 2; ++f) {
            f32x16 da = __builtin_amdgcn_mfma_f32_32x32x16_bf16(Aa, B[f], zero, 0, 0, 0);
            f32x16 db = __builtin_amdgcn_mfma_f32_32x32x16_bf16(Ab, B[f], zero, 0, 0, 0);
#pragma unroll
            for (int i = 0; i < 16; ++i) {
                float ea = da[i], eb = db[i];   // 1 accvgpr_read each
                // guaranteed single 3-input min, rm in arch VGPR
                asm("v_min3_f32 %0, %0, %1, %2"
                    : "+v"(rm[f][i]) : "v"(ea), "v"(eb));
            }
        }
    }

    // ---- epilogue (once per wave): tree-min + cross-half + atomic ----
    unsigned* o = keys + (size_t)dir * TOTPTS + (size_t)b * NPTS;
#pragma unroll
    for (int f = 0; f < 2; ++f) {
        float v = rm[f][0];
#pragma unroll
        for (int i = 1; i < 16; ++i) v = fminf(v, rm[f][i]);
        v = fminf(v, __shfl_xor(v, 32, 64));   // rows split across lane halves
        if (l < 32) {
            unsigned bb = __float_as_uint(v);
            atomicMin(&o[xw + f * 32 + l],
                      bb ^ ((bb & 0x80000000u) ? 0xFFFFFFFFu : 0x80000000u));
        }
    }
}

// Decode key, add hx, sqrt; write mins_seeds; per-wave partial sums.
__global__ void __launch_bounds__(TPB) finalize_kernel(
        const unsigned* __restrict__ keys,
        const float* __restrict__ T, const float* __restrict__ P,
        float* __restrict__ out, float* __restrict__ partials)
{
    int i   = blockIdx.x * TPB + threadIdx.x;   // 0 .. 2*TOTPTS-1
    int dir = (i >= TOTPTS) ? 1 : 0;            // uniform per block
    int idx = i - dir * TOTPTS;
    int b   = idx >> 13;
    int x   = idx & (NPTS - 1);

    unsigned k  = keys[i];
    unsigned bb = (k & 0x80000000u) ? (k ^ 0x80000000u) : ~k;
    float m = __uint_as_float(bb);

    const float* xp = (dir ? P : T) + ((size_t)b * NPTS + x) * 3;
    float a0 = xp[0], a1 = xp[1], a2 = xp[2];
    float hx = 0.5f * (a0 * a0 + a1 * a1 + a2 * a2);
    float d  = sqrtf(fmaxf(2.0f * (hx + m), 0.0f));
    if (dir) out[1 + idx] = d;                  // mins_seeds

#pragma unroll
    for (int off = 32; off > 0; off >>= 1)
        d += __shfl_down(d, off, 64);
    if ((threadIdx.x & 63) == 0) partials[i >> 6] = d;
}

__global__ void scalar_kernel(const float* __restrict__ partials,
                              float* __restrict__ out) {
    int t = threadIdx.x;                        // 64 threads
    float s = 0.0f;
#pragma unroll
    for (int k = 0; k < NPARTIAL / 64; ++k)
        s += partials[t * (NPARTIAL / 64) + k];
#pragma unroll
    for (int off = 32; off > 0; off >>= 1)
        s += __shfl_down(s, off, 64);
    if (t == 0) out[0] = s * (1.0f / (float)TOTPTS);
}

extern "C" void kernel_launch(void* const* d_in, const int* in_sizes, int n_in,
                              void* d_out, int out_size, void* d_ws, size_t ws_size,
                              hipStream_t stream) {
    const float* truep = (const float*)d_in[0];   // [4, 8192, 3] fp32
    const float* predp = (const float*)d_in[1];   // [4, 8192, 3] fp32
    float* out = (float*)d_out;                   // [1 + 32768] fp32

    unsigned* keys     = (unsigned*)d_ws;                 // 2*TOTPTS u32
    float*    partials = (float*)(keys + 2 * TOTPTS);     // 1024 floats

    // 0xFFFFFFFF = max flip-key: valid floor for atomicMin. 256 KB.
    hipMemsetAsync(keys, 0xFF, (size_t)2 * TOTPTS * 4, stream);

    dim3 grid(GXB, GYB, 2 * NB);                  // (32, 16, 8) = 4096 blocks
    nnmin_mfma<<<grid, TPB, 0, stream>>>(truep, predp, keys);

    finalize_kernel<<<(2 * TOTPTS) / TPB, TPB, 0, stream>>>(
        keys, truep, predp, out, partials);
    scalar_kernel<<<1, 64, 0, stream>>>(partials, out);
}

// Round 13
// 86.177 us; speedup vs baseline: 8.9605x; 1.0073x over previous
//
#include <hip/hip_runtime.h>

typedef __attribute__((ext_vector_type(8)))  short bf16x8;   // 8 bf16 = 4 VGPRs
typedef __attribute__((ext_vector_type(16))) float f32x16;   // MFMA 32x32 C/D
typedef __attribute__((ext_vector_type(4)))  float v4f;

#define TPB    256
#define NPTS   8192
#define NB     4
#define TOTPTS (NB * NPTS)        // 32768
#define XWAVE  64                 // x per wave (2 B-frags)
#define XBLK   (4 * XWAVE)        // 256 x per block
#define YTILE  1024               // y per block (R11: 512) — amortize fixed/block cost
#define NTILES (YTILE / 32)       // 32 MFMA tiles
#define GXB    (NPTS / XBLK)      // 32
#define GYB    (NPTS / YTILE)     // 8
#define NPARTIAL ((2 * TOTPTS) / 64)

// ---------------------------------------------------------------------------
// R12 lesson: 3-deep pipeline (8 f32x16 in flight, launch_bounds(256,2))
// device-aborted — REVERTED to R11's verified loop. R13 change is config-only:
// YTILE 512->1024. Rationale: R11's per-block VALU work ~0.8us vs ~2us/block
// wall — the gap is fixed per-block cost (cold global A/B staging latency,
// barrier, epilogue, turnover) paid 16x per CU. Doubling per-block compute
// halves that fraction; LDS 32KB still allows 5 blocks/CU.
// Kept from R11: asm-pinned v_min3 combine (1.5 inst/output), unroll 2,
// launch_bounds(256,1) (R10: cap 128 -> AGPR-form rm, 43us busy),
// flip-key atomicMin combine, 3-launch structure (fixed ~40us harness
// re-poison of ws is dispatch-count-independent — R11 profile).
// Encoding (HW-verified R7):
//   A (y, M) k: [yh0,yl0,yh0, yh1,yl1,yh1, yh2,yl2,yh2, hyh,hyl, 0...]
//   B (x, N) k: [-xh0,-xh0,-xl0, -xh1,-xh1,-xl1, -xh2,-xh2,-xl2, 1,1, 0...]
//   dot = hy - (xh.yh + xh.yl + xl.yh); C/D row = (reg&3)+8(reg>>2)+4(l>>5)
// ---------------------------------------------------------------------------

__device__ __forceinline__ short bfr(float f) {       // fp32->bf16 RNE
    unsigned u = __float_as_uint(f);
    return (short)((u + 0x7FFFu + ((u >> 16) & 1u)) >> 16);
}
__device__ __forceinline__ float bf2f(short s) {
    return __uint_as_float(((unsigned)(unsigned short)s) << 16);
}

// grid = (GXB, GYB, 2*NB) = (32, 8, 8) = 2048 blocks, 4 waves each.
// Wave owns 64 x (2 B-frags); block stages YTILE=1024 y as A-frags in LDS.
__global__ void __launch_bounds__(TPB, 1) nnmin_mfma(
        const float* __restrict__ T, const float* __restrict__ P,
        unsigned* __restrict__ keys)
{
    __shared__ v4f sA[NTILES * 64];   // A-fragments, 32 KB

    const int z   = blockIdx.z;
    const int dir = z >> 2;
    const int b   = z & 3;
    const float* Xb = (dir ? P : T) + (size_t)b * NPTS * 3;
    const float* Yb = (dir ? T : P) + (size_t)b * NPTS * 3;
    const int t     = threadIdx.x;
    const int l     = t & 63;          // lane
    const int w     = t >> 6;          // wave id (0..3)
    const int ybase = blockIdx.y * YTILE;
    const int xw    = blockIdx.x * XBLK + w * XWAVE;   // wave's 64 x

    // ---- stage A-fragments: 4 y-points per thread, 2 LDS entries each ----
    for (int p = t; p < YTILE; p += TPB) {
        const float* yp = Yb + (size_t)(ybase + p) * 3;
        float y0 = yp[0], y1 = yp[1], y2 = yp[2];
        short yh0 = bfr(y0); short yl0 = bfr(y0 - bf2f(yh0));
        short yh1 = bfr(y1); short yl1 = bfr(y1 - bf2f(yh1));
        short yh2 = bfr(y2); short yl2 = bfr(y2 - bf2f(yh2));
        float hy  = 0.5f * (y0 * y0 + y1 * y1 + y2 * y2);
        short hyh = bfr(hy); short hyl = bfr(hy - bf2f(hyh));
        int tile = p >> 5, m = p & 31;
        union { short s[8]; v4f v; } e0, e1;
        e0.s[0] = yh0; e0.s[1] = yl0; e0.s[2] = yh0; e0.s[3] = yh1;
        e0.s[4] = yl1; e0.s[5] = yh1; e0.s[6] = yh2; e0.s[7] = yl2;
        e1.s[0] = yh2; e1.s[1] = hyh; e1.s[2] = hyl; e1.s[3] = 0;
        e1.s[4] = 0;   e1.s[5] = 0;   e1.s[6] = 0;   e1.s[7] = 0;
        sA[tile * 64 + m]      = e0.v;   // lanes <32 read k=0..7
        sA[tile * 64 + 32 + m] = e1.v;   // lanes >=32 read k=8..15
    }

    // ---- build the wave's 2 B-fragments (x side), register-resident ----
    const int   kh  = l >> 5;          // which K-half this lane supplies
    const short ONE = 0x3F80;          // bf16(1.0)
    bf16x8 B[2];
#pragma unroll
    for (int f = 0; f < 2; ++f) {
        const float* xp = Xb + (size_t)(xw + f * 32 + (l & 31)) * 3;
        float nx = -xp[0], ny = -xp[1], nz = -xp[2];
        short h0 = bfr(nx); short lo0 = bfr(nx - bf2f(h0));
        short h1 = bfr(ny); short lo1 = bfr(ny - bf2f(h1));
        short h2 = bfr(nz); short lo2 = bfr(nz - bf2f(h2));
        union { short s[8]; bf16x8 v; } e;
        if (kh == 0) {
            e.s[0] = h0; e.s[1] = h0; e.s[2] = lo0; e.s[3] = h1;
            e.s[4] = h1; e.s[5] = lo1; e.s[6] = h2; e.s[7] = h2;
        } else {
            e.s[0] = lo2; e.s[1] = ONE; e.s[2] = ONE; e.s[3] = 0;
            e.s[4] = 0;   e.s[5] = 0;   e.s[6] = 0;   e.s[7] = 0;
        }
        B[f] = e.v;
    }
    __syncthreads();

    // ---- main loop: 2 ds_read_b128 + 4 MFMA + 64 accvgpr_read + 32 min3 ----
    f32x16 zero = {0.f};               // loop-invariant C input
    float rm[2][16];                   // running mins — pinned to arch VGPRs
#pragma unroll
    for (int f = 0; f < 2; ++f)
#pragma unroll
        for (int i = 0; i < 16; ++i) rm[f][i] = 3.0e38f;

#pragma unroll 2                       // bound A-frag hoisting (R9 spilled)
    for (int tl = 0; tl < NTILES; tl += 2) {
        v4f a4a = sA[(tl + 0) * 64 + l];
        v4f a4b = sA[(tl + 1) * 64 + l];
        bf16x8 Aa = *(bf16x8*)&a4a;
        bf16x8 Ab = *(bf16x8*)&a4b;
#pragma unroll
        for (int f = 0; f < 2; ++f) {
            f32x16 da = __builtin_amdgcn_mfma_f32_32x32x16_bf16(Aa, B[f], zero, 0, 0, 0);
            f32x16 db = __builtin_amdgcn_mfma_f32_32x32x16_bf16(Ab, B[f], zero, 0, 0, 0);
#pragma unroll
            for (int i = 0; i < 16; ++i) {
                float ea = da[i], eb = db[i];   // 1 accvgpr_read each
                asm("v_min3_f32 %0, %0, %1, %2"
                    : "+v"(rm[f][i]) : "v"(ea), "v"(eb));
            }
        }
    }

    // ---- epilogue (once per wave): tree-min + cross-half + atomic ----
    unsigned* o = keys + (size_t)dir * TOTPTS + (size_t)b * NPTS;
#pragma unroll
    for (int f = 0; f < 2; ++f) {
        float v = rm[f][0];
#pragma unroll
        for (int i = 1; i < 16; ++i) v = fminf(v, rm[f][i]);
        v = fminf(v, __shfl_xor(v, 32, 64));   // rows split across lane halves
        if (l < 32) {
            unsigned bb = __float_as_uint(v);
            atomicMin(&o[xw + f * 32 + l],
                      bb ^ ((bb & 0x80000000u) ? 0xFFFFFFFFu : 0x80000000u));
        }
    }
}

// Decode key, add hx, sqrt; write mins_seeds; per-wave partial sums.
__global__ void __launch_bounds__(TPB) finalize_kernel(
        const unsigned* __restrict__ keys,
        const float* __restrict__ T, const float* __restrict__ P,
        float* __restrict__ out, float* __restrict__ partials)
{
    int i   = blockIdx.x * TPB + threadIdx.x;   // 0 .. 2*TOTPTS-1
    int dir = (i >= TOTPTS) ? 1 : 0;            // uniform per block
    int idx = i - dir * TOTPTS;
    int b   = idx >> 13;
    int x   = idx & (NPTS - 1);

    unsigned k  = keys[i];
    unsigned bb = (k & 0x80000000u) ? (k ^ 0x80000000u) : ~k;
    float m = __uint_as_float(bb);

    const float* xp = (dir ? P : T) + ((size_t)b * NPTS + x) * 3;
    float a0 = xp[0], a1 = xp[1], a2 = xp[2];
    float hx = 0.5f * (a0 * a0 + a1 * a1 + a2 * a2);
    float d  = sqrtf(fmaxf(2.0f * (hx + m), 0.0f));
    if (dir) out[1 + idx] = d;                  // mins_seeds

#pragma unroll
    for (int off = 32; off > 0; off >>= 1)
        d += __shfl_down(d, off, 64);
    if ((threadIdx.x & 63) == 0) partials[i >> 6] = d;
}

__global__ void scalar_kernel(const float* __restrict__ partials,
                              float* __restrict__ out) {
    int t = threadIdx.x;                        // 64 threads
    float s = 0.0f;
#pragma unroll
    for (int k = 0; k < NPARTIAL / 64; ++k)
        s += partials[t * (NPARTIAL / 64) + k];
#pragma unroll
    for (int off = 32; off > 0; off >>= 1)
        s += __shfl_down(s, off, 64);
    if (t == 0) out[0] = s * (1.0f / (float)TOTPTS);
}

extern "C" void kernel_launch(void* const* d_in, const int* in_sizes, int n_in,
                              void* d_out, int out_size, void* d_ws, size_t ws_size,
                              hipStream_t stream) {
    const float* truep = (const float*)d_in[0];   // [4, 8192, 3] fp32
    const float* predp = (const float*)d_in[1];   // [4, 8192, 3] fp32
    float* out = (float*)d_out;                   // [1 + 32768] fp32

    unsigned* keys     = (unsigned*)d_ws;                 // 2*TOTPTS u32
    float*    partials = (float*)(keys + 2 * TOTPTS);     // 1024 floats

    // 0xFFFFFFFF = max flip-key: valid floor for atomicMin. 256 KB.
    hipMemsetAsync(keys, 0xFF, (size_t)2 * TOTPTS * 4, stream);

    dim3 grid(GXB, GYB, 2 * NB);                  // (32, 8, 8) = 2048 blocks
    nnmin_mfma<<<grid, TPB, 0, stream>>>(truep, predp, keys);

    finalize_kernel<<<(2 * TOTPTS) / TPB, TPB, 0, stream>>>(
        keys, truep, predp, out, partials);
    scalar_kernel<<<1, 64, 0, stream>>>(partials, out);
}

// Round 16
// 85.249 us; speedup vs baseline: 9.0581x; 1.0109x over previous
//
#include <hip/hip_runtime.h>

typedef __attribute__((ext_vector_type(8)))  short bf16x8;   // 8 bf16 = 4 VGPRs
typedef __attribute__((ext_vector_type(16))) float f32x16;   // MFMA 32x32 C/D
typedef __attribute__((ext_vector_type(4)))  float v4f;

#define TPB    256
#define NPTS   8192
#define NB     4
#define TOTPTS (NB * NPTS)        // 32768
#define XWAVE  64                 // x per wave (2 B-frags) — R13 verified
#define XBLK   (4 * XWAVE)        // 256 x per block
#define YTILE  1024               // y per block
#define NTILES (YTILE / 32)       // 32 MFMA tiles
#define GXB    (NPTS / XBLK)      // 32
#define GYB    (NPTS / YTILE)     // 8 y-chunks
#define NSLICE (2 * NB)           // 8 (dir,batch) slices per chunk
#define WS2_FLOATS ((size_t)GYB * NSLICE * NPTS)  // 512K floats = 2 MB
#define NPARTIAL ((2 * TOTPTS) / 64)   // 1024

// ---------------------------------------------------------------------------
// R14/R15 lesson: the XWAVE=32 + launch_bounds(256,4) retune produced a
// DETERMINISTIC wrong scalar (bit-identical across two different reduction
// structures) — bug is inside that nnmin config (likely codegen under the
// 128-VGPR cap with asm operands); not localizable headlessly. ABANDONED.
// R16 = R13's nnmin VERBATIM (passing, 86.2us) with safe plumbing changes:
//   * atomicMin + 0xFF-memset  ->  plain stores to disjoint per-(chunk,z)
//     slices (R3/R6-validated; no init; memset dispatch deleted).
//     ws2 = 2MB only (R6's regression was 16MB x 64 strided loads; here
//     finalize does 8 loads from 2MB, L2-resident).
//   * finalize min-reduces 8 chunks; separate scalar kernel kept (kernel
//     boundary is the only proven cross-XCD flush — R14).
// Kept intact: asm-pinned v_min3 (R11), launch_bounds(256,1) (R10 cap
// lesson), unroll 2 (R9 hoist/spill lesson), tree-once epilogue (R7 lesson).
// ~40us of total dur is the harness 0xAA ws re-poison fill (untouchable).
// Encoding (HW-verified R7):
//   A (y, M) k: [yh0,yl0,yh0, yh1,yl1,yh1, yh2,yl2,yh2, hyh,hyl, 0...]
//   B (x, N) k: [-xh0,-xh0,-xl0, -xh1,-xh1,-xl1, -xh2,-xh2,-xl2, 1,1, 0...]
//   dot = hy - (xh.yh + xh.yl + xl.yh); C/D: col=lane&31 (x side),
//   row=(reg&3)+8(reg>>2)+4(lane>>5) (y side).
// ---------------------------------------------------------------------------

__device__ __forceinline__ short bfr(float f) {       // fp32->bf16 RNE
    unsigned u = __float_as_uint(f);
    return (short)((u + 0x7FFFu + ((u >> 16) & 1u)) >> 16);
}
__device__ __forceinline__ float bf2f(short s) {
    return __uint_as_float(((unsigned)(unsigned short)s) << 16);
}

// grid = (GXB, GYB, 2*NB) = (32, 8, 8) = 2048 blocks, 4 waves each.
// Wave owns 64 x (2 B-frags); block stages YTILE=1024 y as A-frags in LDS.
__global__ void __launch_bounds__(TPB, 1) nnmin_mfma(
        const float* __restrict__ T, const float* __restrict__ P,
        float* __restrict__ ws2)
{
    __shared__ v4f sA[NTILES * 64];   // A-fragments, 32 KB

    const int z   = blockIdx.z;
    const int dir = z >> 2;
    const int b   = z & 3;
    const float* Xb = (dir ? P : T) + (size_t)b * NPTS * 3;
    const float* Yb = (dir ? T : P) + (size_t)b * NPTS * 3;
    const int t     = threadIdx.x;
    const int l     = t & 63;          // lane
    const int w     = t >> 6;          // wave id (0..3)
    const int ybase = blockIdx.y * YTILE;
    const int xw    = blockIdx.x * XBLK + w * XWAVE;   // wave's 64 x

    // ---- stage A-fragments: 4 y-points per thread, 2 LDS entries each ----
    for (int p = t; p < YTILE; p += TPB) {
        const float* yp = Yb + (size_t)(ybase + p) * 3;
        float y0 = yp[0], y1 = yp[1], y2 = yp[2];
        short yh0 = bfr(y0); short yl0 = bfr(y0 - bf2f(yh0));
        short yh1 = bfr(y1); short yl1 = bfr(y1 - bf2f(yh1));
        short yh2 = bfr(y2); short yl2 = bfr(y2 - bf2f(yh2));
        float hy  = 0.5f * (y0 * y0 + y1 * y1 + y2 * y2);
        short hyh = bfr(hy); short hyl = bfr(hy - bf2f(hyh));
        int tile = p >> 5, m = p & 31;
        union { short s[8]; v4f v; } e0, e1;
        e0.s[0] = yh0; e0.s[1] = yl0; e0.s[2] = yh0; e0.s[3] = yh1;
        e0.s[4] = yl1; e0.s[5] = yh1; e0.s[6] = yh2; e0.s[7] = yl2;
        e1.s[0] = yh2; e1.s[1] = hyh; e1.s[2] = hyl; e1.s[3] = 0;
        e1.s[4] = 0;   e1.s[5] = 0;   e1.s[6] = 0;   e1.s[7] = 0;
        sA[tile * 64 + m]      = e0.v;   // lanes <32 read k=0..7
        sA[tile * 64 + 32 + m] = e1.v;   // lanes >=32 read k=8..15
    }

    // ---- build the wave's 2 B-fragments (x side), register-resident ----
    const int   kh  = l >> 5;          // which K-half this lane supplies
    const short ONE = 0x3F80;          // bf16(1.0)
    bf16x8 B[2];
#pragma unroll
    for (int f = 0; f < 2; ++f) {
        const float* xp = Xb + (size_t)(xw + f * 32 + (l & 31)) * 3;
        float nx = -xp[0], ny = -xp[1], nz = -xp[2];
        short h0 = bfr(nx); short lo0 = bfr(nx - bf2f(h0));
        short h1 = bfr(ny); short lo1 = bfr(ny - bf2f(h1));
        short h2 = bfr(nz); short lo2 = bfr(nz - bf2f(h2));
        union { short s[8]; bf16x8 v; } e;
        if (kh == 0) {
            e.s[0] = h0; e.s[1] = h0; e.s[2] = lo0; e.s[3] = h1;
            e.s[4] = h1; e.s[5] = lo1; e.s[6] = h2; e.s[7] = h2;
        } else {
            e.s[0] = lo2; e.s[1] = ONE; e.s[2] = ONE; e.s[3] = 0;
            e.s[4] = 0;   e.s[5] = 0;   e.s[6] = 0;   e.s[7] = 0;
        }
        B[f] = e.v;
    }
    __syncthreads();

    // ---- main loop: 2 ds_read_b128 + 4 MFMA + 64 accvgpr_read + 32 min3 ----
    f32x16 zero = {0.f};               // loop-invariant C input
    float rm[2][16];                   // running mins — pinned to arch VGPRs
#pragma unroll
    for (int f = 0; f < 2; ++f)
#pragma unroll
        for (int i = 0; i < 16; ++i) rm[f][i] = 3.0e38f;

#pragma unroll 2                       // bound A-frag hoisting (R9 spilled)
    for (int tl = 0; tl < NTILES; tl += 2) {
        v4f a4a = sA[(tl + 0) * 64 + l];
        v4f a4b = sA[(tl + 1) * 64 + l];
        bf16x8 Aa = *(bf16x8*)&a4a;
        bf16x8 Ab = *(bf16x8*)&a4b;
#pragma unroll
        for (int f = 0; f < 2; ++f) {
            f32x16 da = __builtin_amdgcn_mfma_f32_32x32x16_bf16(Aa, B[f], zero, 0, 0, 0);
            f32x16 db = __builtin_amdgcn_mfma_f32_32x32x16_bf16(Ab, B[f], zero, 0, 0, 0);
#pragma unroll
            for (int i = 0; i < 16; ++i) {
                float ea = da[i], eb = db[i];   // 1 accvgpr_read each
                asm("v_min3_f32 %0, %0, %1, %2"
                    : "+v"(rm[f][i]) : "v"(ea), "v"(eb));
            }
        }
    }

    // ---- epilogue: tree-min + cross-half + plain store to own slice ----
    float* o = ws2 + ((size_t)blockIdx.y * NSLICE + z) * NPTS;
#pragma unroll
    for (int f = 0; f < 2; ++f) {
        float v = rm[f][0];
#pragma unroll
        for (int i = 1; i < 16; ++i) v = fminf(v, rm[f][i]);
        v = fminf(v, __shfl_xor(v, 32, 64));   // rows split across lane halves
        if (l < 32) o[xw + f * 32 + l] = v;    // disjoint: no atomics, no init
    }
}

// Min-reduce 8 chunk slices, add hx, sqrt; mins_seeds; per-wave partial sums.
__global__ void __launch_bounds__(TPB) finalize_kernel(
        const float* __restrict__ ws2,
        const float* __restrict__ T, const float* __restrict__ P,
        float* __restrict__ out, float* __restrict__ partials)
{
    int i   = blockIdx.x * TPB + threadIdx.x;   // 0 .. 2*TOTPTS-1
    int dir = (i >= TOTPTS) ? 1 : 0;            // uniform per block
    int idx = i - dir * TOTPTS;
    int b   = idx >> 13;
    int x   = idx & (NPTS - 1);

    const float* p0 = ws2 + (size_t)(dir * 4 + b) * NPTS + x;
    float m = 3.0e38f;
#pragma unroll
    for (int c = 0; c < GYB; ++c)               // 8 loads from 2MB (L2)
        m = fminf(m, p0[(size_t)c * NSLICE * NPTS]);

    const float* xp = (dir ? P : T) + ((size_t)b * NPTS + x) * 3;
    float a0 = xp[0], a1 = xp[1], a2 = xp[2];
    float hx = 0.5f * (a0 * a0 + a1 * a1 + a2 * a2);
    float d  = sqrtf(fmaxf(2.0f * (hx + m), 0.0f));
    if (dir) out[1 + idx] = d;                  // mins_seeds

#pragma unroll
    for (int off = 32; off > 0; off >>= 1)
        d += __shfl_down(d, off, 64);
    if ((threadIdx.x & 63) == 0) partials[i >> 6] = d;
}

// Single-wave final reduction (separate launch: kernel boundary is the only
// reliable cross-XCD flush — R14 lesson).
__global__ void scalar_kernel(const float* __restrict__ partials,
                              float* __restrict__ out) {
    int t = threadIdx.x;                        // 64 threads
    float s = 0.0f;
#pragma unroll
    for (int k = 0; k < NPARTIAL / 64; ++k)
        s += partials[t * (NPARTIAL / 64) + k];
#pragma unroll
    for (int off = 32; off > 0; off >>= 1)
        s += __shfl_down(s, off, 64);
    if (t == 0) out[0] = s * (1.0f / (float)TOTPTS);
}

extern "C" void kernel_launch(void* const* d_in, const int* in_sizes, int n_in,
                              void* d_out, int out_size, void* d_ws, size_t ws_size,
                              hipStream_t stream) {
    const float* truep = (const float*)d_in[0];   // [4, 8192, 3] fp32
    const float* predp = (const float*)d_in[1];   // [4, 8192, 3] fp32
    float* out = (float*)d_out;                   // [1 + 32768] fp32

    float* ws2      = (float*)d_ws;               // 2 MB chunk mins (no init)
    float* partials = ws2 + WS2_FLOATS;           // 1024 floats (write-first)

    dim3 grid(GXB, GYB, 2 * NB);                  // (32, 8, 8) = 2048 blocks
    nnmin_mfma<<<grid, TPB, 0, stream>>>(truep, predp, ws2);

    finalize_kernel<<<(2 * TOTPTS) / TPB, TPB, 0, stream>>>(
        ws2, truep, predp, out, partials);
    scalar_kernel<<<1, 64, 0, stream>>>(partials, out);
}

// Round 18
// 83.328 us; speedup vs baseline: 9.2669x; 1.0231x over previous
//
#include <hip/hip_runtime.h>

typedef __attribute__((ext_vector_type(4)))  short bf16x4;   // 4 bf16 = 2 VGPRs
typedef __attribute__((ext_vector_type(16))) float f32x16;   // MFMA 32x32 C/D

#define TPB    256
#define NPTS   8192
#define NB     4
#define TOTPTS (NB * NPTS)        // 32768
#define XWAVE  64                 // x per wave (2 B-frags)
#define XBLK   (4 * XWAVE)        // 256 x per block
#define YTILE  1024               // y per block
#define NTILES (YTILE / 32)       // 32 MFMA tiles
#define GXB    (NPTS / XBLK)      // 32
#define GYB    (NPTS / YTILE)     // 8 y-chunks
#define NSLICE (2 * NB)           // 8 (dir,batch) slices per chunk
#define WS2_FLOATS ((size_t)GYB * NSLICE * NPTS)  // 512K floats = 2 MB
#define NPARTIAL ((2 * TOTPTS) / 64)   // 1024

// ---------------------------------------------------------------------------
// R17 failed on a NAME COLLISION only: `short4` is a HIP built-in vector
// type; renamed to bf16x4. The compile error also CONFIRMED that
// __builtin_amdgcn_mfma_f32_32x32x8bf16_1k exists on gfx950 and takes a
// 4-short ext_vector. Theory unchanged:
// K=16 -> K=8 (we used 11/16 slots; round the QUERY side to bf16 to fit 8):
//   A (y, M) k: [yh0,yl0, yh1,yl1 | yh2,yl2, hyh,hyl]   (y compensated)
//   B (x, N) k: [-xh0,-xh0, -xh1,-xh1 | -xh2,-xh2, 1,1] (x bf16-rounded)
//   t' = hy - xh.y — exact distance field for ROUNDED query xh; finalize
//   uses hx = 0.5|xh|^2 (identical rounding) so d = |xh - y|; error vs true
//   d <= |x - xh| ~ 2^-9|x| ~ 0.01 worst (threshold 0.036).
// Gains: MFMA cycles ~halve (cycles ∝ K), ds_read_b64, shorter MFMA->min3
// chain. Combine + plumbing byte-identical to R16 (passing, 85.2us).
// Forensics: R10 plain fminf => accvgpr churn (VOP3 can't source AGPRs) ->
// asm-pinned v_min3. R9 full unroll hoists ds_reads -> unroll 2. R14/R15
// XWAVE=32+lb(256,4) deterministically corrupt -> avoided. R4/R14 cross-
// block data only via kernel boundary -> separate finalize+scalar. ~40us of
// total dur is the harness 0xAA ws re-poison fill (untouchable).
// ---------------------------------------------------------------------------

__device__ __forceinline__ short bfr(float f) {       // fp32->bf16 RNE
    unsigned u = __float_as_uint(f);
    return (short)((u + 0x7FFFu + ((u >> 16) & 1u)) >> 16);
}
__device__ __forceinline__ float bf2f(short s) {
    return __uint_as_float(((unsigned)(unsigned short)s) << 16);
}

// grid = (GXB, GYB, 2*NB) = (32, 8, 8) = 2048 blocks, 4 waves each.
// Wave owns 64 x (2 B-frags); block stages YTILE=1024 y as A-frags in LDS.
__global__ void __launch_bounds__(TPB, 1) nnmin_mfma(
        const float* __restrict__ T, const float* __restrict__ P,
        float* __restrict__ ws2)
{
    __shared__ bf16x4 sA[NTILES * 64];   // A-fragments, 16 KB

    const int z   = blockIdx.z;
    const int dir = z >> 2;
    const int b   = z & 3;
    const float* Xb = (dir ? P : T) + (size_t)b * NPTS * 3;
    const float* Yb = (dir ? T : P) + (size_t)b * NPTS * 3;
    const int t     = threadIdx.x;
    const int l     = t & 63;          // lane
    const int w     = t >> 6;          // wave id (0..3)
    const int ybase = blockIdx.y * YTILE;
    const int xw    = blockIdx.x * XBLK + w * XWAVE;   // wave's 64 x

    // ---- stage A-fragments: y compensated hi/lo, hy split ----
    for (int p = t; p < YTILE; p += TPB) {
        const float* yp = Yb + (size_t)(ybase + p) * 3;
        float y0 = yp[0], y1 = yp[1], y2 = yp[2];
        short yh0 = bfr(y0); short yl0 = bfr(y0 - bf2f(yh0));
        short yh1 = bfr(y1); short yl1 = bfr(y1 - bf2f(yh1));
        short yh2 = bfr(y2); short yl2 = bfr(y2 - bf2f(yh2));
        float hy  = 0.5f * (y0 * y0 + y1 * y1 + y2 * y2);
        short hyh = bfr(hy); short hyl = bfr(hy - bf2f(hyh));
        int tile = p >> 5, m = p & 31;
        bf16x4 e0 = {yh0, yl0, yh1, yl1};   // k = 0..3  (lanes < 32)
        bf16x4 e1 = {yh2, yl2, hyh, hyl};   // k = 4..7  (lanes >= 32)
        sA[tile * 64 + m]      = e0;
        sA[tile * 64 + 32 + m] = e1;
    }

    // ---- build the wave's 2 B-fragments: x bf16-rounded, negated ----
    const int   kh  = l >> 5;          // which K-half this lane supplies
    const short ONE = 0x3F80;          // bf16(1.0)
    bf16x4 B[2];
#pragma unroll
    for (int f = 0; f < 2; ++f) {
        const float* xp = Xb + (size_t)(xw + f * 32 + (l & 31)) * 3;
        short h0 = bfr(-xp[0]);        // RNE is sign-symmetric: = -bfr(xp[0])
        short h1 = bfr(-xp[1]);
        short h2 = bfr(-xp[2]);
        bf16x4 e;
        if (kh == 0) e = (bf16x4){h0, h0, h1, h1};
        else         e = (bf16x4){h2, h2, ONE, ONE};
        B[f] = e;
    }
    __syncthreads();

    // ---- main loop: 2 ds_read_b64 + 4 MFMA(K=8) + 32 asm min3 ----
    f32x16 zero = {0.f};               // loop-invariant C input
    float rm[2][16];                   // running mins — pinned to arch VGPRs
#pragma unroll
    for (int f = 0; f < 2; ++f)
#pragma unroll
        for (int i = 0; i < 16; ++i) rm[f][i] = 3.0e38f;

#pragma unroll 2                       // bound A-frag hoisting (R9 spilled)
    for (int tl = 0; tl < NTILES; tl += 2) {
        bf16x4 Aa = sA[(tl + 0) * 64 + l];
        bf16x4 Ab = sA[(tl + 1) * 64 + l];
#pragma unroll
        for (int f = 0; f < 2; ++f) {
            f32x16 da = __builtin_amdgcn_mfma_f32_32x32x8bf16_1k(Aa, B[f], zero, 0, 0, 0);
            f32x16 db = __builtin_amdgcn_mfma_f32_32x32x8bf16_1k(Ab, B[f], zero, 0, 0, 0);
#pragma unroll
            for (int i = 0; i < 16; ++i) {
                float ea = da[i], eb = db[i];
                asm("v_min3_f32 %0, %0, %1, %2"
                    : "+v"(rm[f][i]) : "v"(ea), "v"(eb));
            }
        }
    }

    // ---- epilogue: tree-min + cross-half + plain store to own slice ----
    float* o = ws2 + ((size_t)blockIdx.y * NSLICE + z) * NPTS;
#pragma unroll
    for (int f = 0; f < 2; ++f) {
        float v = rm[f][0];
#pragma unroll
        for (int i = 1; i < 16; ++i) v = fminf(v, rm[f][i]);
        v = fminf(v, __shfl_xor(v, 32, 64));   // rows split across lane halves
        if (l < 32) o[xw + f * 32 + l] = v;    // disjoint: no atomics, no init
    }
}

// Min-reduce 8 chunk slices, add hx(ROUNDED x), sqrt; mins_seeds; wave sums.
__global__ void __launch_bounds__(TPB) finalize_kernel(
        const float* __restrict__ ws2,
        const float* __restrict__ T, const float* __restrict__ P,
        float* __restrict__ out, float* __restrict__ partials)
{
    int i   = blockIdx.x * TPB + threadIdx.x;   // 0 .. 2*TOTPTS-1
    int dir = (i >= TOTPTS) ? 1 : 0;            // uniform per block
    int idx = i - dir * TOTPTS;
    int b   = idx >> 13;
    int x   = idx & (NPTS - 1);

    const float* p0 = ws2 + (size_t)(dir * 4 + b) * NPTS + x;
    float m = 3.0e38f;
#pragma unroll
    for (int c = 0; c < GYB; ++c)               // 8 loads from 2MB (L2)
        m = fminf(m, p0[(size_t)c * NSLICE * NPTS]);

    // hx from the SAME bf16 rounding the MFMA B-side used: d = |xh - y|
    const float* xp = (dir ? P : T) + ((size_t)b * NPTS + x) * 3;
    float a0 = bf2f(bfr(xp[0]));
    float a1 = bf2f(bfr(xp[1]));
    float a2 = bf2f(bfr(xp[2]));
    float hx = 0.5f * (a0 * a0 + a1 * a1 + a2 * a2);
    float d  = sqrtf(fmaxf(2.0f * (hx + m), 0.0f));
    if (dir) out[1 + idx] = d;                  // mins_seeds

#pragma unroll
    for (int off = 32; off > 0; off >>= 1)
        d += __shfl_down(d, off, 64);
    if ((threadIdx.x & 63) == 0) partials[i >> 6] = d;
}

// Single-wave final reduction (separate launch: kernel boundary is the only
// reliable cross-XCD flush — R14 lesson).
__global__ void scalar_kernel(const float* __restrict__ partials,
                              float* __restrict__ out) {
    int t = threadIdx.x;                        // 64 threads
    float s = 0.0f;
#pragma unroll
    for (int k = 0; k < NPARTIAL / 64; ++k)
        s += partials[t * (NPARTIAL / 64) + k];
#pragma unroll
    for (int off = 32; off > 0; off >>= 1)
        s += __shfl_down(s, off, 64);
    if (t == 0) out[0] = s * (1.0f / (float)TOTPTS);
}

extern "C" void kernel_launch(void* const* d_in, const int* in_sizes, int n_in,
                              void* d_out, int out_size, void* d_ws, size_t ws_size,
                              hipStream_t stream) {
    const float* truep = (const float*)d_in[0];   // [4, 8192, 3] fp32
    const float* predp = (const float*)d_in[1];   // [4, 8192, 3] fp32
    float* out = (float*)d_out;                   // [1 + 32768] fp32

    float* ws2      = (float*)d_ws;               // 2 MB chunk mins (no init)
    float* partials = ws2 + WS2_FLOATS;           // 1024 floats (write-first)

    dim3 grid(GXB, GYB, 2 * NB);                  // (32, 8, 8) = 2048 blocks
    nnmin_mfma<<<grid, TPB, 0, stream>>>(truep, predp, ws2);

    finalize_kernel<<<(2 * TOTPTS) / TPB, TPB, 0, stream>>>(
        ws2, truep, predp, out, partials);
    scalar_kernel<<<1, 64, 0, stream>>>(partials, out);
}